// Round 6
// baseline (267.288 us; speedup 1.0000x reference)
//
#include <hip/hip_runtime.h>
#include <stdint.h>

// ---------------------------------------------------------------------------
// Threefry-2x32, 20 rounds — bit-exact match of JAX's threefry2x32 primitive.
// ---------------------------------------------------------------------------
#define TF_ROUND(x0, x1, r)                    \
  {                                            \
    x0 += x1;                                  \
    x1 = (x1 << (r)) | (x1 >> (32 - (r)));     \
    x1 ^= x0;                                  \
  }

__host__ __device__ inline void threefry2x32(uint32_t k0, uint32_t k1,
                                             uint32_t x0, uint32_t x1,
                                             uint32_t& o0, uint32_t& o1) {
  const uint32_t ks2 = k0 ^ k1 ^ 0x1BD11BDAu;
  x0 += k0; x1 += k1;
  TF_ROUND(x0, x1, 13) TF_ROUND(x0, x1, 15) TF_ROUND(x0, x1, 26) TF_ROUND(x0, x1, 6)
  x0 += k1; x1 += ks2 + 1u;
  TF_ROUND(x0, x1, 17) TF_ROUND(x0, x1, 29) TF_ROUND(x0, x1, 16) TF_ROUND(x0, x1, 24)
  x0 += ks2; x1 += k0 + 2u;
  TF_ROUND(x0, x1, 13) TF_ROUND(x0, x1, 15) TF_ROUND(x0, x1, 26) TF_ROUND(x0, x1, 6)
  x0 += k0; x1 += k1 + 3u;
  TF_ROUND(x0, x1, 17) TF_ROUND(x0, x1, 29) TF_ROUND(x0, x1, 16) TF_ROUND(x0, x1, 24)
  x0 += k1; x1 += ks2 + 4u;
  TF_ROUND(x0, x1, 13) TF_ROUND(x0, x1, 15) TF_ROUND(x0, x1, 26) TF_ROUND(x0, x1, 6)
  x0 += ks2; x1 += k0 + 5u;
  o0 = x0; o1 = x1;
}

// Partitionable-mode 32-bit random bits for flat index i: xor of both words
// of a threefry block with counter (0, i).
__device__ inline uint32_t random_bits32(uint32_t k0, uint32_t k1, uint32_t i) {
  uint32_t y0, y1;
  threefry2x32(k0, k1, 0u, i, y0, y1);
  return y0 ^ y1;
}

// ---------------------------------------------------------------------------
// Problem constants (shapes fixed by the reference).
// ---------------------------------------------------------------------------
constexpr int B = 16;
constexpr int N = 1024;
constexpr int G = 2000;
constexpr int NUM_ROWS = B * N;                 // 16384
constexpr int RANK = G - 800 - 1;               // 1199: 0-based kthvalue index
constexpr long long EXPR_ELEMS = (long long)NUM_ROWS * G;  // 32,768,000

// ---------------------------------------------------------------------------
// Kernel 1: expression mask (VERIFIED bit-exact in rounds 3-5). One
// 256-thread block per (b,n) row; exact kthvalue via 256-bucket histogram
// select on the 23-bit mantissa integers. Output int32.
// ---------------------------------------------------------------------------
__global__ __launch_bounds__(256) void expr_mask_kernel(int32_t* __restrict__ out,
                                                        uint32_t ke0,
                                                        uint32_t ke1) {
  __shared__ uint32_t sm[G];
  __shared__ uint32_t hist[256];
  __shared__ uint32_t scan[256];
  __shared__ uint32_t cand[256];
  __shared__ uint32_t s_cnt;
  __shared__ uint32_t s_bucket;
  __shared__ uint32_t s_kk;
  __shared__ uint32_t s_thr;

  const int row = blockIdx.x;
  const int t = threadIdx.x;
  const long long rowbase = (long long)row * G;

  hist[t] = 0u;
  if (t == 0) s_cnt = 0u;
  __syncthreads();

  // Generate the row's 2000 random values (as 23-bit ints) + histogram.
  for (int g = t; g < G; g += 256) {
    uint32_t bits = random_bits32(ke0, ke1, (uint32_t)(rowbase + g));
    uint32_t m = bits >> 9;  // 23-bit mantissa bits; monotone with uniform
    sm[g] = m;
    atomicAdd(&hist[m >> 15], 1u);
  }
  __syncthreads();

  // Inclusive Hillis-Steele scan over the 256 bucket counts.
  uint32_t v = hist[t];
  scan[t] = v;
  __syncthreads();
  for (int off = 1; off < 256; off <<= 1) {
    uint32_t add = (t >= off) ? scan[t - off] : 0u;
    __syncthreads();
    scan[t] += add;
    __syncthreads();
  }
  uint32_t incl = scan[t];
  uint32_t excl = incl - v;
  if (excl <= (uint32_t)RANK && (uint32_t)RANK < incl) {
    s_bucket = (uint32_t)t;
    s_kk = (uint32_t)RANK - excl;
  }
  __syncthreads();

  // Collect the target bucket's candidates (~8 expected; clamp at 256 so even
  // an impossible overflow can't corrupt adjacent LDS).
  const uint32_t bucket = s_bucket;
  for (int g = t; g < G; g += 256) {
    uint32_t m = sm[g];
    if ((m >> 15) == bucket) {
      uint32_t p = atomicAdd(&s_cnt, 1u);
      if (p < 256u) cand[p] = m;
    }
  }
  __syncthreads();

  // Exact rank among candidates (stable tie-break -> ranks are a permutation).
  const uint32_t c = (s_cnt < 256u) ? s_cnt : 256u;
  const uint32_t kk = s_kk;
  if ((uint32_t)t < c) {
    uint32_t mv = cand[t];
    uint32_t r = 0;
    for (uint32_t j = 0; j < c; ++j) {
      uint32_t mj = cand[j];
      r += (mj < mv) || (mj == mv && j < (uint32_t)t);
    }
    if (r == kk) s_thr = mv;
  }
  __syncthreads();

  const uint32_t thr = s_thr;
  for (int g = t; g < G; g += 256) {
    out[rowbase + g] = (sm[g] >= thr) ? 1 : 0;
  }
}

// ---------------------------------------------------------------------------
// Kernel 2: position mask. One thread per (b,n). Modern JAX randint:
//   k1, k2 = split(key); higher = bits32(k1, shape); lower = bits32(k2, shape)
//   offset = ((higher % 3) * 1 + lower % 3) % 3       (multiplier = 1)
// Sub-keys (ah,al / bh,bl) are derived host-side; bits are 32-bit xor-folded
// at counter i (0..16383), matching the verified expr path.
// ---------------------------------------------------------------------------
__global__ __launch_bounds__(256) void pos_mask_kernel(
    int32_t* __restrict__ out,
    uint32_t kr0, uint32_t kr1,
    uint32_t ah0, uint32_t ah1, uint32_t al0, uint32_t al1,
    uint32_t bh0, uint32_t bh1, uint32_t bl0, uint32_t bl1) {
  const int i = blockIdx.x * 256 + threadIdx.x;
  if (i >= NUM_ROWS) return;

  // r = uniform(kr, (B,N), float32)[i]
  uint32_t rb = random_bits32(kr0, kr1, (uint32_t)i);
  union { uint32_t u; float f; } cvt;
  cvt.u = (rb >> 9) | 0x3F800000u;
  float r = cvt.f - 1.0f;

  const float THR2 = (float)(0.33 * 0.3);  // POS_MASK_RATIO * 0.3 (double->f32)
  const float THR1 = (float)0.33;          // POS_MASK_RATIO
  bool two = r < THR2;
  bool one = (r < THR1) && !two;

  // randint(k1, (B,N), 0, 3): split-based double draw, multiplier = 1.
  uint32_t ah = random_bits32(ah0, ah1, (uint32_t)i);
  uint32_t al = random_bits32(al0, al1, (uint32_t)i);
  int dim1 = (int)(((ah % 3u) + (al % 3u)) % 3u);

  uint32_t bh = random_bits32(bh0, bh1, (uint32_t)i);
  uint32_t bl = random_bits32(bl0, bl1, (uint32_t)i);
  int excl = (int)(((bh % 3u) + (bl % 3u)) % 3u);

  int o[3];
#pragma unroll
  for (int d = 0; d < 3; ++d) {
    bool mval = two ? (d != excl) : (one ? (d == dim1) : false);
    o[d] = mval ? 1 : 0;
  }
  long long base = (long long)i * 3;
  out[base + 0] = o[0];
  out[base + 1] = o[1];
  out[base + 2] = o[2];
}

// ---------------------------------------------------------------------------
// Launch
// ---------------------------------------------------------------------------
extern "C" void kernel_launch(void* const* d_in, const int* in_sizes, int n_in,
                              void* d_out, int out_size, void* d_ws, size_t ws_size,
                              hipStream_t stream) {
  (void)d_in; (void)in_sizes; (void)n_in; (void)d_ws; (void)ws_size; (void)out_size;

  // Host-side key derivation (partitionable fold-like split — verified by
  // Output 0 passing since round 3):
  //   base = key(42) = (0, 42)
  //   ke, kp   = split(base)    -> TF(base,(0,0)), TF(base,(0,1))
  //   kr,k1,k2 = split(kp, 3)   -> TF(kp,(0,j)), j=0..2
  //   randint internal: split(k1) -> ah,al ; split(k2) -> bh,bl
  uint32_t ke0, ke1, kp0, kp1;
  threefry2x32(0u, 42u, 0u, 0u, ke0, ke1);
  threefry2x32(0u, 42u, 0u, 1u, kp0, kp1);
  uint32_t kr0, kr1, ka0, ka1, kb0, kb1;
  threefry2x32(kp0, kp1, 0u, 0u, kr0, kr1);
  threefry2x32(kp0, kp1, 0u, 1u, ka0, ka1);
  threefry2x32(kp0, kp1, 0u, 2u, kb0, kb1);
  uint32_t ah0, ah1, al0, al1, bh0, bh1, bl0, bl1;
  threefry2x32(ka0, ka1, 0u, 0u, ah0, ah1);
  threefry2x32(ka0, ka1, 0u, 1u, al0, al1);
  threefry2x32(kb0, kb1, 0u, 0u, bh0, bh1);
  threefry2x32(kb0, kb1, 0u, 1u, bl0, bl1);

  int32_t* out_expr = (int32_t*)d_out;
  int32_t* out_pos = out_expr + EXPR_ELEMS;

  expr_mask_kernel<<<NUM_ROWS, 256, 0, stream>>>(out_expr, ke0, ke1);
  pos_mask_kernel<<<(NUM_ROWS + 255) / 256, 256, 0, stream>>>(
      out_pos, kr0, kr1, ah0, ah1, al0, al1, bh0, bh1, bl0, bl1);
}

// Round 7
// 246.012 us; speedup vs baseline: 1.0865x; 1.0865x over previous
//
#include <hip/hip_runtime.h>
#include <stdint.h>

// ---------------------------------------------------------------------------
// Threefry-2x32, 20 rounds — bit-exact match of JAX's threefry2x32 primitive.
// ---------------------------------------------------------------------------
#define TF_ROUND(x0, x1, r)                    \
  {                                            \
    x0 += x1;                                  \
    x1 = (x1 << (r)) | (x1 >> (32 - (r)));     \
    x1 ^= x0;                                  \
  }

__host__ __device__ inline void threefry2x32(uint32_t k0, uint32_t k1,
                                             uint32_t x0, uint32_t x1,
                                             uint32_t& o0, uint32_t& o1) {
  const uint32_t ks2 = k0 ^ k1 ^ 0x1BD11BDAu;
  x0 += k0; x1 += k1;
  TF_ROUND(x0, x1, 13) TF_ROUND(x0, x1, 15) TF_ROUND(x0, x1, 26) TF_ROUND(x0, x1, 6)
  x0 += k1; x1 += ks2 + 1u;
  TF_ROUND(x0, x1, 17) TF_ROUND(x0, x1, 29) TF_ROUND(x0, x1, 16) TF_ROUND(x0, x1, 24)
  x0 += ks2; x1 += k0 + 2u;
  TF_ROUND(x0, x1, 13) TF_ROUND(x0, x1, 15) TF_ROUND(x0, x1, 26) TF_ROUND(x0, x1, 6)
  x0 += k0; x1 += k1 + 3u;
  TF_ROUND(x0, x1, 17) TF_ROUND(x0, x1, 29) TF_ROUND(x0, x1, 16) TF_ROUND(x0, x1, 24)
  x0 += k1; x1 += ks2 + 4u;
  TF_ROUND(x0, x1, 13) TF_ROUND(x0, x1, 15) TF_ROUND(x0, x1, 26) TF_ROUND(x0, x1, 6)
  x0 += ks2; x1 += k0 + 5u;
  o0 = x0; o1 = x1;
}

// Partitionable-mode 32-bit random bits for flat index i: xor of both words
// of a threefry block with counter (0, i).
__device__ inline uint32_t random_bits32(uint32_t k0, uint32_t k1, uint32_t i) {
  uint32_t y0, y1;
  threefry2x32(k0, k1, 0u, i, y0, y1);
  return y0 ^ y1;
}

// ---------------------------------------------------------------------------
// Problem constants (shapes fixed by the reference).
// ---------------------------------------------------------------------------
constexpr int B = 16;
constexpr int N = 1024;
constexpr int G = 2000;
constexpr int NUM_ROWS = B * N;                 // 16384
constexpr int RANK = G - 800 - 1;               // 1199: 0-based kthvalue index
constexpr long long EXPR_ELEMS = (long long)NUM_ROWS * G;  // 32,768,000
constexpr int PER_THREAD = 8;                   // 250 threads x 8 = 2000
constexpr int ACTIVE_T = G / PER_THREAD;        // 250

// ---------------------------------------------------------------------------
// Kernel 1: expression mask (bit-exact, verified R3-R6). One 256-thread block
// per (b,n) row. Register-resident rewrite: thread t owns the 8 contiguous
// counters row*2000 + 8t + j, so candidate-collection and output compare
// registers instead of re-reading an LDS array (the R6 profile showed 232
// VALU ops/elem vs ~70 for threefry — the excess was LDS passes + 64-bit
// addressing). Output via 2x int4 stores (wave writes 512 contiguous ints).
// ---------------------------------------------------------------------------
__global__ __launch_bounds__(256) void expr_mask_kernel(int32_t* __restrict__ out,
                                                        uint32_t ke0,
                                                        uint32_t ke1) {
  __shared__ uint32_t hist[256];
  __shared__ uint32_t scan[256];
  __shared__ uint32_t cand[256];
  __shared__ uint32_t s_cnt;
  __shared__ uint32_t s_bucket;
  __shared__ uint32_t s_kk;
  __shared__ uint32_t s_thr;

  const int t = threadIdx.x;
  const uint32_t rowstart = (uint32_t)blockIdx.x * (uint32_t)G;
  const uint32_t base = rowstart + (uint32_t)t * (uint32_t)PER_THREAD;
  const bool active = (t < ACTIVE_T);

  hist[t] = 0u;
  if (t == 0) s_cnt = 0u;
  __syncthreads();

  // Generate this thread's 8 values (23-bit mantissa ints) into registers +
  // histogram on the top 8 bits.
  uint32_t m[PER_THREAD];
  if (active) {
#pragma unroll
    for (int j = 0; j < PER_THREAD; ++j) {
      uint32_t bits = random_bits32(ke0, ke1, base + (uint32_t)j);
      m[j] = bits >> 9;
      atomicAdd(&hist[m[j] >> 15], 1u);
    }
  }
  __syncthreads();

  // Inclusive Hillis-Steele scan over the 256 bucket counts.
  uint32_t v = hist[t];
  scan[t] = v;
  __syncthreads();
  for (int off = 1; off < 256; off <<= 1) {
    uint32_t add = (t >= off) ? scan[t - off] : 0u;
    __syncthreads();
    scan[t] += add;
    __syncthreads();
  }
  uint32_t incl = scan[t];
  uint32_t excl = incl - v;
  if (excl <= (uint32_t)RANK && (uint32_t)RANK < incl) {
    s_bucket = (uint32_t)t;
    s_kk = (uint32_t)RANK - excl;
  }
  __syncthreads();

  // Collect the target bucket's candidates (~8 expected; clamp at 256).
  const uint32_t bucket = s_bucket;
  if (active) {
#pragma unroll
    for (int j = 0; j < PER_THREAD; ++j) {
      if ((m[j] >> 15) == bucket) {
        uint32_t p = atomicAdd(&s_cnt, 1u);
        if (p < 256u) cand[p] = m[j];
      }
    }
  }
  __syncthreads();

  // Exact rank among candidates (stable tie-break -> ranks are a permutation).
  const uint32_t c = (s_cnt < 256u) ? s_cnt : 256u;
  const uint32_t kk = s_kk;
  if ((uint32_t)t < c) {
    uint32_t mv = cand[t];
    uint32_t r = 0;
    for (uint32_t j = 0; j < c; ++j) {
      uint32_t mj = cand[j];
      r += (mj < mv) || (mj == mv && j < (uint32_t)t);
    }
    if (r == kk) s_thr = mv;
  }
  __syncthreads();

  const uint32_t thr = s_thr;
  if (active) {
    int4 a, b;
    a.x = (m[0] >= thr) ? 1 : 0;
    a.y = (m[1] >= thr) ? 1 : 0;
    a.z = (m[2] >= thr) ? 1 : 0;
    a.w = (m[3] >= thr) ? 1 : 0;
    b.x = (m[4] >= thr) ? 1 : 0;
    b.y = (m[5] >= thr) ? 1 : 0;
    b.z = (m[6] >= thr) ? 1 : 0;
    b.w = (m[7] >= thr) ? 1 : 0;
    int4* p = (int4*)(out + base);
    p[0] = a;
    p[1] = b;
  }
}

// ---------------------------------------------------------------------------
// Kernel 2: position mask (bit-exact, verified R6). One thread per (b,n).
// randint: k1,k2 = split(key); offset = (bits32(k1,i)%3 + bits32(k2,i)%3) % 3.
// ---------------------------------------------------------------------------
__global__ __launch_bounds__(256) void pos_mask_kernel(
    int32_t* __restrict__ out,
    uint32_t kr0, uint32_t kr1,
    uint32_t ah0, uint32_t ah1, uint32_t al0, uint32_t al1,
    uint32_t bh0, uint32_t bh1, uint32_t bl0, uint32_t bl1) {
  const int i = blockIdx.x * 256 + threadIdx.x;
  if (i >= NUM_ROWS) return;

  // r = uniform(kr, (B,N), float32)[i]
  uint32_t rb = random_bits32(kr0, kr1, (uint32_t)i);
  union { uint32_t u; float f; } cvt;
  cvt.u = (rb >> 9) | 0x3F800000u;
  float r = cvt.f - 1.0f;

  const float THR2 = (float)(0.33 * 0.3);  // POS_MASK_RATIO * 0.3 (double->f32)
  const float THR1 = (float)0.33;          // POS_MASK_RATIO
  bool two = r < THR2;
  bool one = (r < THR1) && !two;

  uint32_t ah = random_bits32(ah0, ah1, (uint32_t)i);
  uint32_t al = random_bits32(al0, al1, (uint32_t)i);
  int dim1 = (int)(((ah % 3u) + (al % 3u)) % 3u);

  uint32_t bh = random_bits32(bh0, bh1, (uint32_t)i);
  uint32_t bl = random_bits32(bl0, bl1, (uint32_t)i);
  int excl = (int)(((bh % 3u) + (bl % 3u)) % 3u);

  int o[3];
#pragma unroll
  for (int d = 0; d < 3; ++d) {
    bool mval = two ? (d != excl) : (one ? (d == dim1) : false);
    o[d] = mval ? 1 : 0;
  }
  long long obase = (long long)i * 3;
  out[obase + 0] = o[0];
  out[obase + 1] = o[1];
  out[obase + 2] = o[2];
}

// ---------------------------------------------------------------------------
// Launch
// ---------------------------------------------------------------------------
extern "C" void kernel_launch(void* const* d_in, const int* in_sizes, int n_in,
                              void* d_out, int out_size, void* d_ws, size_t ws_size,
                              hipStream_t stream) {
  (void)d_in; (void)in_sizes; (void)n_in; (void)d_ws; (void)ws_size; (void)out_size;

  // Host-side key derivation (partitionable fold-like split — verified):
  //   base = key(42) = (0, 42)
  //   ke, kp   = split(base)    -> TF(base,(0,0)), TF(base,(0,1))
  //   kr,k1,k2 = split(kp, 3)   -> TF(kp,(0,j)), j=0..2
  //   randint internal: split(k1) -> ah,al ; split(k2) -> bh,bl
  uint32_t ke0, ke1, kp0, kp1;
  threefry2x32(0u, 42u, 0u, 0u, ke0, ke1);
  threefry2x32(0u, 42u, 0u, 1u, kp0, kp1);
  uint32_t kr0, kr1, ka0, ka1, kb0, kb1;
  threefry2x32(kp0, kp1, 0u, 0u, kr0, kr1);
  threefry2x32(kp0, kp1, 0u, 1u, ka0, ka1);
  threefry2x32(kp0, kp1, 0u, 2u, kb0, kb1);
  uint32_t ah0, ah1, al0, al1, bh0, bh1, bl0, bl1;
  threefry2x32(ka0, ka1, 0u, 0u, ah0, ah1);
  threefry2x32(ka0, ka1, 0u, 1u, al0, al1);
  threefry2x32(kb0, kb1, 0u, 0u, bh0, bh1);
  threefry2x32(kb0, kb1, 0u, 1u, bl0, bl1);

  int32_t* out_expr = (int32_t*)d_out;
  int32_t* out_pos = out_expr + EXPR_ELEMS;

  expr_mask_kernel<<<NUM_ROWS, 256, 0, stream>>>(out_expr, ke0, ke1);
  pos_mask_kernel<<<(NUM_ROWS + 255) / 256, 256, 0, stream>>>(
      out_pos, kr0, kr1, ah0, ah1, al0, al1, bh0, bh1, bl0, bl1);
}

// Round 8
// 242.442 us; speedup vs baseline: 1.1025x; 1.0147x over previous
//
#include <hip/hip_runtime.h>
#include <stdint.h>

// ---------------------------------------------------------------------------
// Threefry-2x32, 20 rounds — bit-exact match of JAX's threefry2x32 primitive.
// ---------------------------------------------------------------------------
#define TF_ROUND(x0, x1, r)                    \
  {                                            \
    x0 += x1;                                  \
    x1 = (x1 << (r)) | (x1 >> (32 - (r)));     \
    x1 ^= x0;                                  \
  }

__host__ __device__ inline void threefry2x32(uint32_t k0, uint32_t k1,
                                             uint32_t x0, uint32_t x1,
                                             uint32_t& o0, uint32_t& o1) {
  const uint32_t ks2 = k0 ^ k1 ^ 0x1BD11BDAu;
  x0 += k0; x1 += k1;
  TF_ROUND(x0, x1, 13) TF_ROUND(x0, x1, 15) TF_ROUND(x0, x1, 26) TF_ROUND(x0, x1, 6)
  x0 += k1; x1 += ks2 + 1u;
  TF_ROUND(x0, x1, 17) TF_ROUND(x0, x1, 29) TF_ROUND(x0, x1, 16) TF_ROUND(x0, x1, 24)
  x0 += ks2; x1 += k0 + 2u;
  TF_ROUND(x0, x1, 13) TF_ROUND(x0, x1, 15) TF_ROUND(x0, x1, 26) TF_ROUND(x0, x1, 6)
  x0 += k0; x1 += k1 + 3u;
  TF_ROUND(x0, x1, 17) TF_ROUND(x0, x1, 29) TF_ROUND(x0, x1, 16) TF_ROUND(x0, x1, 24)
  x0 += k1; x1 += ks2 + 4u;
  TF_ROUND(x0, x1, 13) TF_ROUND(x0, x1, 15) TF_ROUND(x0, x1, 26) TF_ROUND(x0, x1, 6)
  x0 += ks2; x1 += k0 + 5u;
  o0 = x0; o1 = x1;
}

// Partitionable-mode 32-bit random bits for flat index i: xor of both words
// of a threefry block with counter (0, i).
__device__ inline uint32_t random_bits32(uint32_t k0, uint32_t k1, uint32_t i) {
  uint32_t y0, y1;
  threefry2x32(k0, k1, 0u, i, y0, y1);
  return y0 ^ y1;
}

// ---------------------------------------------------------------------------
// Problem constants (shapes fixed by the reference).
// ---------------------------------------------------------------------------
constexpr int B = 16;
constexpr int N = 1024;
constexpr int G = 2000;
constexpr int NUM_ROWS = B * N;                 // 16384
constexpr uint32_t RANK = (uint32_t)(G - 800 - 1);  // 1199
constexpr long long EXPR_ELEMS = (long long)NUM_ROWS * G;  // 32,768,000
constexpr int PER_THREAD = 8;                   // 250 threads x 8 = 2000
constexpr int ACTIVE_T = G / PER_THREAD;        // 250

typedef int v4i __attribute__((ext_vector_type(4)));

// ---------------------------------------------------------------------------
// Fused kernel: one 256-thread block per (b,n) row.
//   threads 0..249 : expr mask — 8 register-resident values each, histogram
//                    on top-8 bits, exact kthvalue select (verified R3-R7)
//   threads 250..254: the 5 pos-mask threefry draws for this row (same wave
//                    as tail of generation -> ~70 extra wave-ops, hidden)
//   thread 255     : pos-mask combine + store (runs during wave-0 scan)
// Scan: single-wave butterfly over 64 lanes x 4 buckets (no barriers),
// replacing the 16-barrier Hillis-Steele. 5 barriers/block total.
// ---------------------------------------------------------------------------
__global__ __launch_bounds__(256) void fused_mask_kernel(
    int32_t* __restrict__ out_expr, int32_t* __restrict__ out_pos,
    uint32_t ke0, uint32_t ke1,
    uint32_t kr0, uint32_t kr1,
    uint32_t ah0, uint32_t ah1, uint32_t al0, uint32_t al1,
    uint32_t bh0, uint32_t bh1, uint32_t bl0, uint32_t bl1) {
  __shared__ alignas(16) uint32_t hist[256];
  __shared__ uint32_t cand[256];
  __shared__ uint32_t s_posbits[5];
  __shared__ uint32_t s_cnt;
  __shared__ uint32_t s_bucket;
  __shared__ uint32_t s_kk;
  __shared__ uint32_t s_thr;

  const int t = threadIdx.x;
  const uint32_t row = blockIdx.x;
  const uint32_t base = row * (uint32_t)G + (uint32_t)t * (uint32_t)PER_THREAD;
  const bool active = (t < ACTIVE_T);

  hist[t] = 0u;
  if (t == 0) s_cnt = 0u;
  __syncthreads();  // barrier 1

  // --- Generation: expr values into registers + histogram; pos bits in the
  // --- idle tail lanes of wave 3.
  uint32_t m[PER_THREAD];
  if (active) {
#pragma unroll
    for (int j = 0; j < PER_THREAD; ++j) {
      uint32_t bits = random_bits32(ke0, ke1, base + (uint32_t)j);
      m[j] = bits >> 9;  // 23-bit mantissa int; monotone with the f32 uniform
      atomicAdd(&hist[m[j] >> 15], 1u);
    }
  } else if (t < 255) {
    // t = 250..254 -> draws 0..4: r, ah, al, bh, bl
    uint32_t pk0, pk1;
    switch (t) {
      case 250: pk0 = kr0; pk1 = kr1; break;
      case 251: pk0 = ah0; pk1 = ah1; break;
      case 252: pk0 = al0; pk1 = al1; break;
      case 253: pk0 = bh0; pk1 = bh1; break;
      default:  pk0 = bl0; pk1 = bl1; break;
    }
    s_posbits[t - 250] = random_bits32(pk0, pk1, row);
  }
  __syncthreads();  // barrier 2

  // --- Wave 0: butterfly scan over 256 buckets (4 per lane), find the bucket
  // --- holding rank RANK. No barriers inside.
  if (t < 64) {
    uint4 h = reinterpret_cast<const uint4*>(hist)[t];
    uint32_t tot = h.x + h.y + h.z + h.w;
    uint32_t x = tot;
#pragma unroll
    for (int d = 1; d < 64; d <<= 1) {
      uint32_t o = __shfl_up(x, d, 64);
      if (t >= d) x += o;
    }
    uint32_t e0 = x - tot;          // exclusive prefix of bucket 4t
    uint32_t e1 = e0 + h.x;
    uint32_t e2 = e1 + h.y;
    uint32_t e3 = e2 + h.z;
    if (e0 <= RANK && RANK < e1) { s_bucket = 4u * t + 0u; s_kk = RANK - e0; }
    if (e1 <= RANK && RANK < e2) { s_bucket = 4u * t + 1u; s_kk = RANK - e1; }
    if (e2 <= RANK && RANK < e3) { s_bucket = 4u * t + 2u; s_kk = RANK - e2; }
    if (e3 <= RANK && RANK < e3 + h.w) { s_bucket = 4u * t + 3u; s_kk = RANK - e3; }
  } else if (t == 255) {
    // --- Pos-mask combine (bit-exact logic from the verified pos kernel).
    uint32_t rb = s_posbits[0];
    union { uint32_t u; float f; } cvt;
    cvt.u = (rb >> 9) | 0x3F800000u;
    float r = cvt.f - 1.0f;
    const float THR2 = (float)(0.33 * 0.3);
    const float THR1 = (float)0.33;
    bool two = r < THR2;
    bool one = (r < THR1) && !two;
    int dim1 = (int)(((s_posbits[1] % 3u) + (s_posbits[2] % 3u)) % 3u);
    int excl = (int)(((s_posbits[3] % 3u) + (s_posbits[4] % 3u)) % 3u);
    uint32_t obase = row * 3u;
#pragma unroll
    for (int d = 0; d < 3; ++d) {
      bool mval = two ? (d != excl) : (one ? (d == dim1) : false);
      out_pos[obase + (uint32_t)d] = mval ? 1 : 0;
    }
  }
  __syncthreads();  // barrier 3

  // --- Collect the target bucket's candidates (~8 expected; clamp at 256).
  const uint32_t bucket = s_bucket;
  if (active) {
#pragma unroll
    for (int j = 0; j < PER_THREAD; ++j) {
      if ((m[j] >> 15) == bucket) {
        uint32_t p = atomicAdd(&s_cnt, 1u);
        if (p < 256u) cand[p] = m[j];
      }
    }
  }
  __syncthreads();  // barrier 4

  // --- Exact rank among candidates (stable tie-break -> permutation).
  const uint32_t c = (s_cnt < 256u) ? s_cnt : 256u;
  const uint32_t kk = s_kk;
  if ((uint32_t)t < c) {
    uint32_t mv = cand[t];
    uint32_t r = 0;
    for (uint32_t j = 0; j < c; ++j) {
      uint32_t mj = cand[j];
      r += (mj < mv) || (mj == mv && j < (uint32_t)t);
    }
    if (r == kk) s_thr = mv;
  }
  __syncthreads();  // barrier 5

  const uint32_t thr = s_thr;
  if (active) {
    v4i a, b;
    a.x = (m[0] >= thr) ? 1 : 0;
    a.y = (m[1] >= thr) ? 1 : 0;
    a.z = (m[2] >= thr) ? 1 : 0;
    a.w = (m[3] >= thr) ? 1 : 0;
    b.x = (m[4] >= thr) ? 1 : 0;
    b.y = (m[5] >= thr) ? 1 : 0;
    b.z = (m[6] >= thr) ? 1 : 0;
    b.w = (m[7] >= thr) ? 1 : 0;
    v4i* p = (v4i*)(out_expr + base);
    __builtin_nontemporal_store(a, p);      // streaming 131 MB, no reuse
    __builtin_nontemporal_store(b, p + 1);
  }
}

// ---------------------------------------------------------------------------
// Launch
// ---------------------------------------------------------------------------
extern "C" void kernel_launch(void* const* d_in, const int* in_sizes, int n_in,
                              void* d_out, int out_size, void* d_ws, size_t ws_size,
                              hipStream_t stream) {
  (void)d_in; (void)in_sizes; (void)n_in; (void)d_ws; (void)ws_size; (void)out_size;

  // Host-side key derivation (partitionable fold-like split — verified):
  //   base = key(42) = (0, 42)
  //   ke, kp   = split(base)    -> TF(base,(0,0)), TF(base,(0,1))
  //   kr,k1,k2 = split(kp, 3)   -> TF(kp,(0,j)), j=0..2
  //   randint internal: split(k1) -> ah,al ; split(k2) -> bh,bl
  uint32_t ke0, ke1, kp0, kp1;
  threefry2x32(0u, 42u, 0u, 0u, ke0, ke1);
  threefry2x32(0u, 42u, 0u, 1u, kp0, kp1);
  uint32_t kr0, kr1, ka0, ka1, kb0, kb1;
  threefry2x32(kp0, kp1, 0u, 0u, kr0, kr1);
  threefry2x32(kp0, kp1, 0u, 1u, ka0, ka1);
  threefry2x32(kp0, kp1, 0u, 2u, kb0, kb1);
  uint32_t ah0, ah1, al0, al1, bh0, bh1, bl0, bl1;
  threefry2x32(ka0, ka1, 0u, 0u, ah0, ah1);
  threefry2x32(ka0, ka1, 0u, 1u, al0, al1);
  threefry2x32(kb0, kb1, 0u, 0u, bh0, bh1);
  threefry2x32(kb0, kb1, 0u, 1u, bl0, bl1);

  int32_t* out_expr = (int32_t*)d_out;
  int32_t* out_pos = out_expr + EXPR_ELEMS;

  fused_mask_kernel<<<NUM_ROWS, 256, 0, stream>>>(
      out_expr, out_pos, ke0, ke1, kr0, kr1,
      ah0, ah1, al0, al1, bh0, bh1, bl0, bl1);
}